// Round 1
// baseline (7707.711 us; speedup 1.0000x reference)
//
#include <hip/hip_runtime.h>

typedef __attribute__((ext_vector_type(8))) _Float16 f16x8;
typedef __attribute__((ext_vector_type(4))) float f32x4;

#define T_STEPS 1024
#define BATCH   128
#define FDIM    128
#define UDIM    256
#define GCOLS   1024   // 4*U
#define NGRP    8      // WGs per batch-group (u-split)
#define ROWS    16     // batch rows per WG
#define USL     32     // u columns per WG
#define KSTEPS  12     // 384 / 32
#define XST     136    // x stage row stride (f16), 128+8 pad
#define HST     264    // h stage row stride (f16), 256+8 pad
#define ZST     24     // z_lds inner stride (f32), 16+8 pad (keeps 16B align)

__global__ __launch_bounds__(256, 1)
void lstm_scan_kernel(const float* __restrict__ xg, const float* __restrict__ Wg,
                      const float* __restrict__ Rg, const float* __restrict__ bg_,
                      float* __restrict__ outg, unsigned int* __restrict__ cnt,
                      float* __restrict__ hbuf)
{
    __shared__ _Float16 xs[ROWS][XST];
    __shared__ _Float16 hs[ROWS][HST];
    __shared__ float    zs[128][ZST];   // [local col][row m]

    const int tid  = threadIdx.x;
    const int lane = tid & 63;
    const int wave = tid >> 6;
    const int bgi  = blockIdx.x & 7;   // batch group == XCD id (round-robin)
    const int ngi  = blockIdx.x >> 3;  // u-slice group
    const int r0   = bgi * ROWS;
    const int u0   = ngi * USL;
    const int lj   = lane & 15;        // MFMA m/n index within tile
    const int lg   = lane >> 4;        // MFMA k-group

    unsigned int* mycnt = cnt + (size_t)bgi * 64;  // 256B apart per group

    // ---- one-time: build B fragments (W;R combined, fp16) in registers ----
    f16x8 bfr[2][KSTEPS];
#pragma unroll
    for (int nt2 = 0; nt2 < 2; ++nt2) {
        const int lc  = (wave * 2 + nt2) * 16 + lj;          // local col 0..127
        const int col = (lc >> 5) * 256 + u0 + (lc & 31);    // global col (gate*256+u)
#pragma unroll
        for (int ks = 0; ks < KSTEPS; ++ks) {
            f16x8 v;
#pragma unroll
            for (int i = 0; i < 8; ++i) {
                const int k = ks * 32 + lg * 8 + i;          // combined K index
                const float w = (k < FDIM) ? Wg[k * GCOLS + col]
                                           : Rg[(k - FDIM) * GCOLS + col];
                v[i] = (_Float16)w;
            }
            bfr[nt2][ks] = v;
        }
    }

    // staging / gate-update thread roles
    const int xrow = tid >> 4;          // row 0..15 (also gate row m)
    const int xf0  = (tid & 15) * 8;    // x chunk base (8 floats)
    const int hc0  = (tid & 15) * 16;   // h chunk base (16 floats)
    const int uu0  = (tid * 2) & 31;    // first of 2 u columns this thread updates

    float bb[4][2];
#pragma unroll
    for (int gi = 0; gi < 4; ++gi) {
#pragma unroll
        for (int s = 0; s < 2; ++s)
            bb[gi][s] = bg_[gi * 256 + u0 + uu0 + s];
    }

    float cc0 = 0.f, cc1 = 0.f;   // cell state (2 elements per thread)

    for (int t = 0; t < T_STEPS; ++t) {
        const int p = t & 1;

        // issue x_t loads early (latency hides under the barrier wait)
        const float* xp = xg + ((size_t)(r0 + xrow) * T_STEPS + (size_t)t) * FDIM + xf0;
        const f32x4 xa = *(const f32x4*)xp;
        const f32x4 xb = *(const f32x4*)(xp + 4);

        // wait for all 8 WGs of this batch group to finish step t-1
        if (t > 0 && tid == 0) {
            const unsigned tgt = (unsigned)(NGRP * t);
            while (__hip_atomic_load(mycnt, __ATOMIC_ACQUIRE, __HIP_MEMORY_SCOPE_AGENT) < tgt) { }
        }
        __syncthreads();

        // stage x_t -> LDS fp16
        {
            f16x8 v;
#pragma unroll
            for (int i = 0; i < 4; ++i) { v[i] = (_Float16)xa[i]; v[4 + i] = (_Float16)xb[i]; }
            *(f16x8*)&xs[xrow][xf0] = v;
        }
        // stage h_{t-1} -> LDS fp16 (t==0 reads zeroed hbuf[0])
        {
            const float* hp = hbuf + ((size_t)p * BATCH + r0 + xrow) * UDIM + hc0;
            const f32x4 h0 = *(const f32x4*)hp;
            const f32x4 h1 = *(const f32x4*)(hp + 4);
            const f32x4 h2 = *(const f32x4*)(hp + 8);
            const f32x4 h3 = *(const f32x4*)(hp + 12);
            f16x8 va, vb;
#pragma unroll
            for (int i = 0; i < 4; ++i) {
                va[i] = (_Float16)h0[i]; va[4 + i] = (_Float16)h1[i];
                vb[i] = (_Float16)h2[i]; vb[4 + i] = (_Float16)h3[i];
            }
            *(f16x8*)&hs[xrow][hc0]     = va;
            *(f16x8*)&hs[xrow][hc0 + 8] = vb;
        }
        __syncthreads();

        // z = [x_t | h] @ [W;R] slice : 12 K-steps, 2 n-tiles per wave
        f32x4 acc0 = {0.f, 0.f, 0.f, 0.f};
        f32x4 acc1 = {0.f, 0.f, 0.f, 0.f};
#pragma unroll
        for (int ks = 0; ks < KSTEPS; ++ks) {
            const f16x8 a = (ks < 4)
                ? *(const f16x8*)&xs[lj][ks * 32 + lg * 8]
                : *(const f16x8*)&hs[lj][(ks - 4) * 32 + lg * 8];
            acc0 = __builtin_amdgcn_mfma_f32_16x16x32_f16(a, bfr[0][ks], acc0, 0, 0, 0);
            acc1 = __builtin_amdgcn_mfma_f32_16x16x32_f16(a, bfr[1][ks], acc1, 0, 0, 0);
        }
        // scatter z fragments to LDS (col-major, 16B-contiguous rows per col)
        {
            const int lc0 = wave * 32 + lj;
            *(f32x4*)&zs[lc0][lg * 4]      = acc0;   // rows lg*4..lg*4+3, col lc0
            *(f32x4*)&zs[lc0 + 16][lg * 4] = acc1;
        }
        __syncthreads();

        // gate math: each thread owns (m=xrow, uu0) and (m, uu0+1)
        float hv0, hv1;
        {
            const int m = xrow;
            float i0 = zs[0 * 32 + uu0][m] + bb[0][0];
            float f0 = zs[1 * 32 + uu0][m] + bb[1][0];
            float g0 = zs[2 * 32 + uu0][m] + bb[2][0];
            float o0 = zs[3 * 32 + uu0][m] + bb[3][0];
            float i1 = zs[0 * 32 + uu0 + 1][m] + bb[0][1];
            float f1 = zs[1 * 32 + uu0 + 1][m] + bb[1][1];
            float g1 = zs[2 * 32 + uu0 + 1][m] + bb[2][1];
            float o1 = zs[3 * 32 + uu0 + 1][m] + bb[3][1];
            i0 = 1.f / (1.f + __expf(-i0));
            f0 = 1.f / (1.f + __expf(-f0));
            o0 = 1.f / (1.f + __expf(-o0));
            i1 = 1.f / (1.f + __expf(-i1));
            f1 = 1.f / (1.f + __expf(-f1));
            o1 = 1.f / (1.f + __expf(-o1));
            cc0 = f0 * cc0 + i0 * g0;      // g is LINEAR (activation=None)
            cc1 = f1 * cc1 + i1 * g1;
            hv0 = o0 * cc0;                // h = o * c (no tanh on cell)
            hv1 = o1 * cc1;
        }

        if (t == T_STEPS - 1) {
            float* op = outg + (size_t)(r0 + xrow) * UDIM + u0 + uu0;
            op[0] = tanhf(hv0);            // post-hoc tanh on last h
            op[1] = tanhf(hv1);
        } else {
            float* hw = hbuf + ((size_t)(p ^ 1) * BATCH + r0 + xrow) * UDIM + u0 + uu0;
            hw[0] = hv0;
            hw[1] = hv1;
            __threadfence();               // publish h before signaling
            __syncthreads();               // all threads' writes fenced
            if (tid == 0)
                __hip_atomic_fetch_add(mycnt, 1u, __ATOMIC_RELEASE, __HIP_MEMORY_SCOPE_AGENT);
        }
    }
}

extern "C" void kernel_launch(void* const* d_in, const int* in_sizes, int n_in,
                              void* d_out, int out_size, void* d_ws, size_t ws_size,
                              hipStream_t stream) {
    const float* x = (const float*)d_in[0];   // [128,1024,128]
    const float* W = (const float*)d_in[1];   // [128,1024]
    const float* R = (const float*)d_in[2];   // [256,1024]
    const float* b = (const float*)d_in[3];   // [1024]
    float* out = (float*)d_out;               // [128,256]

    unsigned char* ws = (unsigned char*)d_ws;
    unsigned int* cnt = (unsigned int*)ws;          // 8 groups * 256B
    float* hbuf = (float*)(ws + 4096);              // [2][128][256] f32

    const size_t clr = 4096 + (size_t)2 * BATCH * UDIM * sizeof(float);
    hipMemsetAsync(d_ws, 0, clr, stream);           // zero counters + h0

    hipLaunchKernelGGL(lstm_scan_kernel, dim3(64), dim3(256), 0, stream,
                       x, W, R, b, out, cnt, hbuf);
}

// Round 2
// 2740.962 us; speedup vs baseline: 2.8120x; 2.8120x over previous
//
#include <hip/hip_runtime.h>

typedef __attribute__((ext_vector_type(8))) _Float16 f16x8;
typedef __attribute__((ext_vector_type(4))) float f32x4;

#define T_STEPS 1024
#define BATCH   128
#define FDIM    128
#define UDIM    256
#define GCOLS   1024   // 4*U
#define NGRP    8      // WGs per batch-group (u-split)
#define ROWS    16     // batch rows per WG
#define USL     32     // u columns per WG
#define KSTEPS  12     // 384 / 32
#define XST     136    // x stage row stride (f16), 128+8 pad
#define HST     264    // h stage row stride (f16), 256+8 pad
#define ZST     24     // z_lds inner stride (f32), 16+8 pad (keeps 16B align)

__global__ __launch_bounds__(256, 1)
void lstm_scan_kernel(const float* __restrict__ xg, const float* __restrict__ Wg,
                      const float* __restrict__ Rg, const float* __restrict__ bg_,
                      float* __restrict__ outg, unsigned int* __restrict__ cnt,
                      float* __restrict__ hbuf)
{
    __shared__ _Float16 xs[ROWS][XST];
    __shared__ _Float16 hs[ROWS][HST];
    __shared__ float    zs[128][ZST];   // [local col][row m]

    const int tid  = threadIdx.x;
    const int lane = tid & 63;
    const int wave = tid >> 6;
    const int bgi  = blockIdx.x & 7;   // batch group
    const int ngi  = blockIdx.x >> 3;  // u-slice group
    const int r0   = bgi * ROWS;
    const int u0   = ngi * USL;
    const int lj   = lane & 15;        // MFMA m/n index within tile
    const int lg   = lane >> 4;        // MFMA k-group

    unsigned int* mycnt = cnt + (size_t)bgi * 64;  // 256B apart per group

    // ---- one-time: build B fragments (W;R combined, fp16) in registers ----
    f16x8 bfr[2][KSTEPS];
#pragma unroll
    for (int nt2 = 0; nt2 < 2; ++nt2) {
        const int lc  = (wave * 2 + nt2) * 16 + lj;          // local col 0..127
        const int col = (lc >> 5) * 256 + u0 + (lc & 31);    // global col (gate*256+u)
#pragma unroll
        for (int ks = 0; ks < KSTEPS; ++ks) {
            f16x8 v;
#pragma unroll
            for (int i = 0; i < 8; ++i) {
                const int k = ks * 32 + lg * 8 + i;          // combined K index
                const float w = (k < FDIM) ? Wg[k * GCOLS + col]
                                           : Rg[(k - FDIM) * GCOLS + col];
                v[i] = (_Float16)w;
            }
            bfr[nt2][ks] = v;
        }
    }

    // staging / gate-update thread roles
    const int xrow = tid >> 4;          // row 0..15 (also gate row m)
    const int xf0  = (tid & 15) * 8;    // x chunk base (8 floats)
    const int hc0  = (tid & 15) * 16;   // h chunk base (16 floats)
    const int uu0  = (tid * 2) & 31;    // first of 2 u columns this thread updates

    float bb[4][2];
#pragma unroll
    for (int gi = 0; gi < 4; ++gi) {
#pragma unroll
        for (int s = 0; s < 2; ++s)
            bb[gi][s] = bg_[gi * 256 + u0 + uu0 + s];
    }

    float cc0 = 0.f, cc1 = 0.f;   // cell state (2 elements per thread)

    for (int t = 0; t < T_STEPS; ++t) {
        const int p = t & 1;

        // issue x_t loads early (latency hides under the barrier wait)
        const float* xp = xg + ((size_t)(r0 + xrow) * T_STEPS + (size_t)t) * FDIM + xf0;
        const f32x4 xa = *(const f32x4*)xp;
        const f32x4 xb = *(const f32x4*)(xp + 4);

        // wait for all 8 WGs of this batch group to finish step t-1
        if (t > 0 && tid == 0) {
            const unsigned tgt = (unsigned)(NGRP * t);
            while (__hip_atomic_load(mycnt, __ATOMIC_RELAXED, __HIP_MEMORY_SCOPE_AGENT) < tgt) { }
        }
        __syncthreads();

        // stage x_t -> LDS fp16
        {
            f16x8 v;
#pragma unroll
            for (int i = 0; i < 4; ++i) { v[i] = (_Float16)xa[i]; v[4 + i] = (_Float16)xb[i]; }
            *(f16x8*)&xs[xrow][xf0] = v;
        }
        // stage h_{t-1} -> LDS fp16 via L3-coherent 64-bit atomic loads
        // (t==0 reads zeroed hbuf[0])
        {
            const unsigned long long* hp = (const unsigned long long*)
                (hbuf + ((size_t)p * BATCH + r0 + xrow) * UDIM + hc0);
            unsigned long long hv[8];
#pragma unroll
            for (int j = 0; j < 8; ++j)
                hv[j] = __hip_atomic_load(hp + j, __ATOMIC_RELAXED, __HIP_MEMORY_SCOPE_AGENT);
            f16x8 va, vb;
#pragma unroll
            for (int j = 0; j < 4; ++j) {
                union { unsigned long long u; float f[2]; } c0, c1;
                c0.u = hv[j];     c1.u = hv[4 + j];
                va[2 * j]     = (_Float16)c0.f[0];
                va[2 * j + 1] = (_Float16)c0.f[1];
                vb[2 * j]     = (_Float16)c1.f[0];
                vb[2 * j + 1] = (_Float16)c1.f[1];
            }
            *(f16x8*)&hs[xrow][hc0]     = va;
            *(f16x8*)&hs[xrow][hc0 + 8] = vb;
        }
        __syncthreads();

        // z = [x_t | h] @ [W;R] slice : 12 K-steps, 2 n-tiles per wave
        f32x4 acc0 = {0.f, 0.f, 0.f, 0.f};
        f32x4 acc1 = {0.f, 0.f, 0.f, 0.f};
#pragma unroll
        for (int ks = 0; ks < KSTEPS; ++ks) {
            const f16x8 a = (ks < 4)
                ? *(const f16x8*)&xs[lj][ks * 32 + lg * 8]
                : *(const f16x8*)&hs[lj][(ks - 4) * 32 + lg * 8];
            acc0 = __builtin_amdgcn_mfma_f32_16x16x32_f16(a, bfr[0][ks], acc0, 0, 0, 0);
            acc1 = __builtin_amdgcn_mfma_f32_16x16x32_f16(a, bfr[1][ks], acc1, 0, 0, 0);
        }
        // scatter z fragments to LDS (col-major, 16B-contiguous rows per col)
        {
            const int lc0 = wave * 32 + lj;
            *(f32x4*)&zs[lc0][lg * 4]      = acc0;   // rows lg*4..lg*4+3, col lc0
            *(f32x4*)&zs[lc0 + 16][lg * 4] = acc1;
        }
        __syncthreads();

        // gate math: each thread owns (m=xrow, uu0) and (m, uu0+1)
        float hv0, hv1;
        {
            const int m = xrow;
            float i0 = zs[0 * 32 + uu0][m] + bb[0][0];
            float f0 = zs[1 * 32 + uu0][m] + bb[1][0];
            float g0 = zs[2 * 32 + uu0][m] + bb[2][0];
            float o0 = zs[3 * 32 + uu0][m] + bb[3][0];
            float i1 = zs[0 * 32 + uu0 + 1][m] + bb[0][1];
            float f1 = zs[1 * 32 + uu0 + 1][m] + bb[1][1];
            float g1 = zs[2 * 32 + uu0 + 1][m] + bb[2][1];
            float o1 = zs[3 * 32 + uu0 + 1][m] + bb[3][1];
            i0 = 1.f / (1.f + __expf(-i0));
            f0 = 1.f / (1.f + __expf(-f0));
            o0 = 1.f / (1.f + __expf(-o0));
            i1 = 1.f / (1.f + __expf(-i1));
            f1 = 1.f / (1.f + __expf(-f1));
            o1 = 1.f / (1.f + __expf(-o1));
            cc0 = f0 * cc0 + i0 * g0;      // g is LINEAR (activation=None)
            cc1 = f1 * cc1 + i1 * g1;
            hv0 = o0 * cc0;                // h = o * c (no tanh on cell)
            hv1 = o1 * cc1;
        }

        if (t == T_STEPS - 1) {
            float* op = outg + (size_t)(r0 + xrow) * UDIM + u0 + uu0;
            op[0] = tanhf(hv0);            // post-hoc tanh on last h
            op[1] = tanhf(hv1);
        } else {
            // publish h via L3-coherent 64-bit atomic store (no cache flush)
            float* hw = hbuf + ((size_t)(p ^ 1) * BATCH + r0 + xrow) * UDIM + u0 + uu0;
            union { float f[2]; unsigned long long u; } pk;
            pk.f[0] = hv0; pk.f[1] = hv1;
            __hip_atomic_store((unsigned long long*)hw, pk.u,
                               __ATOMIC_RELAXED, __HIP_MEMORY_SCOPE_AGENT);
            // __syncthreads drains vmcnt(0) for every thread, so all h stores
            // have reached L3 before tid 0 signals.
            asm volatile("s_waitcnt vmcnt(0)" ::: "memory");
            __syncthreads();
            if (tid == 0)
                __hip_atomic_fetch_add(mycnt, 1u, __ATOMIC_RELAXED, __HIP_MEMORY_SCOPE_AGENT);
        }
    }
}

extern "C" void kernel_launch(void* const* d_in, const int* in_sizes, int n_in,
                              void* d_out, int out_size, void* d_ws, size_t ws_size,
                              hipStream_t stream) {
    const float* x = (const float*)d_in[0];   // [128,1024,128]
    const float* W = (const float*)d_in[1];   // [128,1024]
    const float* R = (const float*)d_in[2];   // [256,1024]
    const float* b = (const float*)d_in[3];   // [1024]
    float* out = (float*)d_out;               // [128,256]

    unsigned char* ws = (unsigned char*)d_ws;
    unsigned int* cnt = (unsigned int*)ws;          // 8 groups * 256B
    float* hbuf = (float*)(ws + 4096);              // [2][128][256] f32

    const size_t clr = 4096 + (size_t)2 * BATCH * UDIM * sizeof(float);
    hipMemsetAsync(d_ws, 0, clr, stream);           // zero counters + h0

    hipLaunchKernelGGL(lstm_scan_kernel, dim3(64), dim3(256), 0, stream,
                       x, W, R, b, out, cnt, hbuf);
}

// Round 3
// 2337.502 us; speedup vs baseline: 3.2974x; 1.1726x over previous
//
#include <hip/hip_runtime.h>

typedef __attribute__((ext_vector_type(8))) _Float16 f16x8;
typedef __attribute__((ext_vector_type(4))) float f32x4;

#define T_STEPS 1024
#define BATCH   128
#define FDIM    128
#define UDIM    256
#define GCOLS   1024   // 4*U
#define NGRP    8      // WGs per batch-group (u-split)
#define ROWS    16     // batch rows per WG
#define USL     32     // u columns per WG
#define KSTEPS  12     // 384 / 32
#define HWPR    128    // h words per row (256 fp16 / 2)
#define XST     136    // x stage row stride (f16), 128+8 pad
#define HST     264    // h stage row stride (f16), 256+8 pad
#define ZST     24     // z_lds inner stride (f32), 16+8 pad (keeps 16B align)

__global__ __launch_bounds__(256, 1)
void lstm_scan_kernel(const float* __restrict__ xg, const float* __restrict__ Wg,
                      const float* __restrict__ Rg, const float* __restrict__ bg_,
                      float* __restrict__ outg, unsigned long long* __restrict__ hbuf)
{
    __shared__ _Float16 xs[ROWS][XST];
    __shared__ _Float16 hs[ROWS][HST];
    __shared__ float    zs[128][ZST];   // [local col][row m]

    const int tid  = threadIdx.x;
    const int lane = tid & 63;
    const int wave = tid >> 6;
    const int bgi  = blockIdx.x & 7;   // batch group
    const int ngi  = blockIdx.x >> 3;  // u-slice group
    const int r0   = bgi * ROWS;
    const int u0   = ngi * USL;
    const int lj   = lane & 15;        // MFMA m/n index within tile
    const int lg   = lane >> 4;        // MFMA k-group

    // ---- one-time: build B fragments (W;R combined, fp16) in registers ----
    f16x8 bfr[2][KSTEPS];
#pragma unroll
    for (int nt2 = 0; nt2 < 2; ++nt2) {
        const int lc  = (wave * 2 + nt2) * 16 + lj;          // local col 0..127
        const int col = (lc >> 5) * 256 + u0 + (lc & 31);    // global col (gate*256+u)
#pragma unroll
        for (int ks = 0; ks < KSTEPS; ++ks) {
            f16x8 v;
#pragma unroll
            for (int i = 0; i < 8; ++i) {
                const int k = ks * 32 + lg * 8 + i;          // combined K index
                const float w = (k < FDIM) ? Wg[k * GCOLS + col]
                                           : Rg[(k - FDIM) * GCOLS + col];
                v[i] = (_Float16)w;
            }
            bfr[nt2][ks] = v;
        }
    }

    // staging / gate-update thread roles
    const int xrow = tid >> 4;          // row 0..15 (also gate row m)
    const int xf0  = (tid & 15) * 8;    // x chunk base (8 floats)
    const int hc0  = (tid & 15) * 16;   // h chunk base (16 fp16 = 8 words)
    const int uu0  = (tid * 2) & 31;    // first of 2 u columns this thread updates

    float bb[4][2];
#pragma unroll
    for (int gi = 0; gi < 4; ++gi) {
#pragma unroll
        for (int s = 0; s < 2; ++s)
            bb[gi][s] = bg_[gi * 256 + u0 + uu0 + s];
    }

    float cc0 = 0.f, cc1 = 0.f;   // cell state (2 elements per thread)

    for (int t = 0; t < T_STEPS; ++t) {
        const int p = t & 1;

        // issue x_t loads early (latency hides under the h poll)
        const float* xp = xg + ((size_t)(r0 + xrow) * T_STEPS + (size_t)t) * FDIM + xf0;
        const f32x4 xa = *(const f32x4*)xp;
        const f32x4 xb = *(const f32x4*)(xp + 4);

        // ---- poll tagged h words: {lo32 = 2 fp16, hi32 = step tag} ----
        // t==0 reads the zeroed buffer (tag 0 == expected, h == 0).
        const unsigned long long* hp =
            hbuf + ((size_t)p * BATCH + r0 + xrow) * HWPR + (hc0 >> 1);
        unsigned long long hv[8];
#pragma unroll
        for (int j = 0; j < 8; ++j)
            hv[j] = __hip_atomic_load(hp + j, __ATOMIC_RELAXED, __HIP_MEMORY_SCOPE_AGENT);
        {
            const unsigned tagt = (unsigned)t;
            while (true) {
                bool ok = true;
#pragma unroll
                for (int j = 0; j < 8; ++j)
                    ok &= ((unsigned)(hv[j] >> 32) == tagt);
                if (ok) break;
#pragma unroll
                for (int j = 0; j < 8; ++j)
                    if ((unsigned)(hv[j] >> 32) != tagt)
                        hv[j] = __hip_atomic_load(hp + j, __ATOMIC_RELAXED,
                                                  __HIP_MEMORY_SCOPE_AGENT);
            }
        }

        // stage x_t -> LDS fp16
        {
            f16x8 v;
#pragma unroll
            for (int i = 0; i < 4; ++i) { v[i] = (_Float16)xa[i]; v[4 + i] = (_Float16)xb[i]; }
            *(f16x8*)&xs[xrow][xf0] = v;
        }
        // stage h -> LDS (already fp16 in the word lo32s, just repack)
        {
            uint4 a, b2;
            a.x = (unsigned)hv[0]; a.y = (unsigned)hv[1];
            a.z = (unsigned)hv[2]; a.w = (unsigned)hv[3];
            b2.x = (unsigned)hv[4]; b2.y = (unsigned)hv[5];
            b2.z = (unsigned)hv[6]; b2.w = (unsigned)hv[7];
            *(uint4*)&hs[xrow][hc0]     = a;
            *(uint4*)&hs[xrow][hc0 + 8] = b2;
        }
        __syncthreads();

        // z = [x_t | h] @ [W;R] slice : 12 K-steps, 2 n-tiles per wave
        f32x4 acc0 = {0.f, 0.f, 0.f, 0.f};
        f32x4 acc1 = {0.f, 0.f, 0.f, 0.f};
#pragma unroll
        for (int ks = 0; ks < KSTEPS; ++ks) {
            const f16x8 a = (ks < 4)
                ? *(const f16x8*)&xs[lj][ks * 32 + lg * 8]
                : *(const f16x8*)&hs[lj][(ks - 4) * 32 + lg * 8];
            acc0 = __builtin_amdgcn_mfma_f32_16x16x32_f16(a, bfr[0][ks], acc0, 0, 0, 0);
            acc1 = __builtin_amdgcn_mfma_f32_16x16x32_f16(a, bfr[1][ks], acc1, 0, 0, 0);
        }
        // scatter z fragments to LDS (col-major, 16B-contiguous rows per col)
        {
            const int lc0 = wave * 32 + lj;
            *(f32x4*)&zs[lc0][lg * 4]      = acc0;   // rows lg*4..lg*4+3, col lc0
            *(f32x4*)&zs[lc0 + 16][lg * 4] = acc1;
        }
        __syncthreads();

        // gate math: each thread owns (m=xrow, uu0) and (m, uu0+1)
        float hv0, hv1;
        {
            const int m = xrow;
            float i0 = zs[0 * 32 + uu0][m] + bb[0][0];
            float f0 = zs[1 * 32 + uu0][m] + bb[1][0];
            float g0 = zs[2 * 32 + uu0][m] + bb[2][0];
            float o0 = zs[3 * 32 + uu0][m] + bb[3][0];
            float i1 = zs[0 * 32 + uu0 + 1][m] + bb[0][1];
            float f1 = zs[1 * 32 + uu0 + 1][m] + bb[1][1];
            float g1 = zs[2 * 32 + uu0 + 1][m] + bb[2][1];
            float o1 = zs[3 * 32 + uu0 + 1][m] + bb[3][1];
            i0 = 1.f / (1.f + __expf(-i0));
            f0 = 1.f / (1.f + __expf(-f0));
            o0 = 1.f / (1.f + __expf(-o0));
            i1 = 1.f / (1.f + __expf(-i1));
            f1 = 1.f / (1.f + __expf(-f1));
            o1 = 1.f / (1.f + __expf(-o1));
            cc0 = f0 * cc0 + i0 * g0;      // g is LINEAR (activation=None)
            cc1 = f1 * cc1 + i1 * g1;
            hv0 = o0 * cc0;                // h = o * c (no tanh on cell)
            hv1 = o1 * cc1;
        }

        if (t == T_STEPS - 1) {
            float* op = outg + (size_t)(r0 + xrow) * UDIM + u0 + uu0;
            op[0] = tanhf(hv0);            // post-hoc tanh on last h
            op[1] = tanhf(hv1);
        } else {
            // publish h as ONE tagged 64-bit atomic word: no fence, no counter
            union { _Float16 h[2]; unsigned lo; } pk;
            pk.h[0] = (_Float16)hv0;
            pk.h[1] = (_Float16)hv1;
            const unsigned long long w =
                ((unsigned long long)(unsigned)(t + 1) << 32) | pk.lo;
            unsigned long long* hw =
                hbuf + ((size_t)(p ^ 1) * BATCH + r0 + xrow) * HWPR + ((u0 + uu0) >> 1);
            __hip_atomic_store(hw, w, __ATOMIC_RELAXED, __HIP_MEMORY_SCOPE_AGENT);
        }
    }
}

extern "C" void kernel_launch(void* const* d_in, const int* in_sizes, int n_in,
                              void* d_out, int out_size, void* d_ws, size_t ws_size,
                              hipStream_t stream) {
    const float* x = (const float*)d_in[0];   // [128,1024,128]
    const float* W = (const float*)d_in[1];   // [128,1024]
    const float* R = (const float*)d_in[2];   // [256,1024]
    const float* b = (const float*)d_in[3];   // [1024]
    float* out = (float*)d_out;               // [128,256]

    unsigned char* ws = (unsigned char*)d_ws;
    unsigned long long* hbuf = (unsigned long long*)(ws + 4096);  // [2][128][128] ull

    // zero tags (tag 0 == "h ready for step 0", h == 0)
    const size_t clr = 4096 + (size_t)2 * BATCH * HWPR * sizeof(unsigned long long);
    hipMemsetAsync(d_ws, 0, clr, stream);

    hipLaunchKernelGGL(lstm_scan_kernel, dim3(64), dim3(256), 0, stream,
                       x, W, R, b, out, hbuf);
}